// Round 5
// baseline (159.833 us; speedup 1.0000x reference)
//
#include <hip/hip_runtime.h>

#define B_SZ 8
#define T_LEN 4096
#define N_DIM 256
#define H_DIM 512
#define NC 32
#define CL 128
#define ROWS (B_SZ * T_LEN)

typedef __attribute__((ext_vector_type(4))) float f32x4;
typedef __attribute__((ext_vector_type(8))) short bf16x8;

static __device__ __forceinline__ unsigned short f2bf(float f) {
    unsigned int u = __float_as_uint(f);
    unsigned int r = (u + 0x7FFFu + ((u >> 16) & 1u)) >> 16;
    return (unsigned short)r;
}
static __device__ __forceinline__ float bf2f(unsigned short s) {
    return __uint_as_float(((unsigned int)s) << 16);
}

static __device__ __forceinline__ void lam_of(const float* __restrict__ nu,
                                              const float* __restrict__ theta,
                                              int h, float& lre, float& lim) {
    float r = __expf(-__expf(nu[h]));
    float th = theta[h];
    lre = r * __cosf(th);
    lim = r * __sinf(th);
}

// ---------- conversion kernels ----------
__global__ __launch_bounds__(256) void conv_x(const float4* __restrict__ x, ushort4* __restrict__ xb) {
    int id = blockIdx.x * 256 + threadIdx.x;
    float4 v = x[id];
    ushort4 o;
    o.x = f2bf(v.x); o.y = f2bf(v.y); o.z = f2bf(v.z); o.w = f2bf(v.w);
    xb[id] = o;
}

// BT1[n][k] (1024 x 256): n=2h -> Bre[k][h], n=2h+1 -> Bim[k][h]
__global__ __launch_bounds__(256) void conv_Bt(const float* __restrict__ Bre,
                                               const float* __restrict__ Bim,
                                               unsigned short* __restrict__ BT1) {
    int id = blockIdx.x * 256 + threadIdx.x;           // id = k*512 + h
    int k = id >> 9, h = id & 511;
    BT1[(long)(2 * h) * 256 + k]     = f2bf(Bre[id]);
    BT1[(long)(2 * h + 1) * 256 + k] = f2bf(Bim[id]);
}

// CT[n][k] (256 x 1024): k=2h -> Cre[h][n], k=2h+1 -> -Cim[h][n]
__global__ __launch_bounds__(256) void conv_Ct(const float* __restrict__ Cre,
                                               const float* __restrict__ Cim,
                                               unsigned short* __restrict__ CT) {
    int id = blockIdx.x * 256 + threadIdx.x;           // id = h*256 + nn
    int h = id >> 8, nn = id & 255;
    CT[(long)nn * 1024 + 2 * h]     = f2bf(Cre[id]);
    CT[(long)nn * 1024 + 2 * h + 1] = f2bf(-Cim[id]);
}

// ---------- K-chunk-resident MFMA GEMM: out = A(MxK) @ Bt(NxK)^T ----------
// R5: the R0-R4 invariant (both GEMMs ~52us regardless of tile/pipeline
// shape, all pipes <20% busy) matches m233's decomposition: ~72% of the
// 2-phase structure's time IS the per-K-step stage+vmcnt+barrier skeleton.
// So remove it: 64x64 tile with a FULL 256-wide K-chunk resident in LDS
// (A 32KB + B 32KB = 64KB -> 2 blocks/CU).  Per chunk: stage 16 glls ->
// __syncthreads -> 8x{4 ds_read_b128 + 4 MFMA} fully unrolled with ZERO
// barriers/waitcnt inside.  K1 = 1 chunk (2 barriers/block total),
// K3 = 4 chunks (8).  Exposed chunk-load latency is covered by the sibling
// resident block.  Bank swizzle: read slot ^= (lane>>4)^(lane&3) with the
// matching pre-swizzled GLOBAL source on the write side (gll writes
// linearly; both-sides-or-neither).  Residual 2-way conflict = free.
// Swapped-operand MFMA (verified in R4): lane holds row=lane&15,
// cols=(lane>>4)*4+r -> vectorized ushort4/float4 epilogue.
// MODE 0: K1 epilogue (scale by gamma[col/2], store bf16)
// MODE 1: K3 epilogue (add D[col]*u[row][col], store f32); u from e1b (bf16) if non-null else e1 (f32)
template <int MODE, int KC>
__global__ __launch_bounds__(256) void gemm_res(const unsigned short* __restrict__ A,
                                                const unsigned short* __restrict__ Bt,
                                                int N,
                                                const float* __restrict__ e0,
                                                const float* __restrict__ e1,
                                                const unsigned short* __restrict__ e1b,
                                                void* __restrict__ out) {
    __shared__ unsigned short As[64 * 256];   // 32 KB, [64 rows][256 k], 512 B/row
    __shared__ unsigned short Bs[64 * 256];   // 32 KB
    const int tid = threadIdx.x;
    const int lane = tid & 63;
    const int wave = tid >> 6;
    const int wr = wave >> 1, wc = wave & 1;

    // XCD-aware swizzle (grid % 8 == 0 for both instantiations)
    const int nwg = (int)gridDim.x;
    const int cpx = nwg >> 3;
    const int bid = (int)blockIdx.x;
    const int tile = (bid & 7) * cpx + (bid >> 3);

    const int nTilesN = N >> 6;
    const long tileM = (long)(tile / nTilesN) * 64;
    const long tileN = (long)(tile % nTilesN) * 64;

    // ---- staging geometry ----
    // 1-KB unit c covers rows {2c, 2c+1}; lane l writes row 2c+(l>>5),
    // 16-B slot (l&31).  Stored content must be global slot s^(row&3)
    // (write-side of the swizzle) -> fetch offset 8*((l&31)^xr) ushorts.
    const int l5 = lane >> 5;
    const int s_lin = lane & 31;

    // ---- read geometry ----
    // frag (row R, k-step kk): global slot kk*4+(lane>>4); stored at slot
    // ^(R&3), and R&3 == lane&3 for 16-aligned frag rows.
    const int rslot = 16 * ((lane >> 4) ^ (lane & 3));        // byte offset
    const int arow = wr * 32 + (lane & 15);
    const int brow = wc * 32 + (lane & 15);

    f32x4 acc[2][2] = {};

    for (int ci = 0; ci < KC / 256; ++ci) {
        if (ci) __syncthreads();                              // WAR: prev chunk consumed
        const int k0 = ci * 256;
#pragma unroll
        for (int cc = 0; cc < 8; ++cc) {
            const int c = wave * 8 + cc;
            const int xr = (2 * (c & 1) + l5) & 3;
            const int sgo = 8 * (s_lin ^ xr);                 // swizzled k-offset (ushorts)
            const unsigned short* ga = A + (tileM + 2 * c + l5) * (long)KC + k0 + sgo;
            __builtin_amdgcn_global_load_lds((const __attribute__((address_space(1))) unsigned int*)ga,
                                             (__attribute__((address_space(3))) unsigned int*)(As + c * 512),
                                             16, 0, 0);
            const unsigned short* gb = Bt + (tileN + 2 * c + l5) * (long)KC + k0 + sgo;
            __builtin_amdgcn_global_load_lds((const __attribute__((address_space(1))) unsigned int*)gb,
                                             (__attribute__((address_space(3))) unsigned int*)(Bs + c * 512),
                                             16, 0, 0);
        }
        __syncthreads();                                      // vmcnt(0) + barrier: chunk resident

#pragma unroll
        for (int kk = 0; kk < 8; ++kk) {
            bf16x8 af[2], bfr[2];
#pragma unroll
            for (int m = 0; m < 2; ++m)
                af[m] = *(const bf16x8*)((const char*)As + (arow + m * 16) * 512 + kk * 64 + rslot);
#pragma unroll
            for (int n = 0; n < 2; ++n)
                bfr[n] = *(const bf16x8*)((const char*)Bs + (brow + n * 16) * 512 + kk * 64 + rslot);
#pragma unroll
            for (int m = 0; m < 2; ++m)
#pragma unroll
                for (int n = 0; n < 2; ++n)
                    acc[m][n] = __builtin_amdgcn_mfma_f32_16x16x32_bf16(bfr[n], af[m], acc[m][n], 0, 0, 0);
        }
    }

    const int fr = lane & 15;
    const int fs = lane >> 4;
    if constexpr (MODE == 0) {
        unsigned short* o = (unsigned short*)out;
#pragma unroll
        for (int n = 0; n < 2; ++n) {
            const int col0 = (int)tileN + wc * 32 + n * 16 + fs * 4;   // multiple of 4
            const int h0 = col0 >> 1;
            const float g0 = __expf(e0[h0]);
            const float g1 = __expf(e0[h0 + 1]);
#pragma unroll
            for (int m = 0; m < 2; ++m) {
                const long grow = tileM + wr * 32 + m * 16 + fr;
                ushort4 pk;
                pk.x = f2bf(acc[m][n][0] * g0);
                pk.y = f2bf(acc[m][n][1] * g0);
                pk.z = f2bf(acc[m][n][2] * g1);
                pk.w = f2bf(acc[m][n][3] * g1);
                *(ushort4*)(o + grow * N + col0) = pk;                 // 8B line-coalesced store
            }
        }
    } else {
        float* o = (float*)out;
#pragma unroll
        for (int n = 0; n < 2; ++n) {
            const int col0 = (int)tileN + wc * 32 + n * 16 + fs * 4;   // multiple of 4
            const float4 dv = *(const float4*)(e0 + col0);
#pragma unroll
            for (int m = 0; m < 2; ++m) {
                const long grow = tileM + wr * 32 + m * 16 + fr;
                const long idx = grow * N + col0;
                float u0, u1, u2, u3;
                if (e1b) {
                    ushort4 ub = *(const ushort4*)(e1b + idx);
                    u0 = bf2f(ub.x); u1 = bf2f(ub.y); u2 = bf2f(ub.z); u3 = bf2f(ub.w);
                } else {
                    float4 uf = *(const float4*)(e1 + idx);
                    u0 = uf.x; u1 = uf.y; u2 = uf.z; u3 = uf.w;
                }
                float4 st;
                st.x = acc[m][n][0] + dv.x * u0;
                st.y = acc[m][n][1] + dv.y * u1;
                st.z = acc[m][n][2] + dv.z * u2;
                st.w = acc[m][n][3] + dv.w * u3;
                *(float4*)(o + idx) = st;                              // 16B line-coalesced store
            }
        }
    }
}

// ---------- scan: sums-first, then fused local-scan-from-carry ----------
// thread handles 2 complex h's (ushort4 = 8B loads, 512B/wave coalesced)

// k2s: read-only chunk sums. sums[(b*NC+c)*256+hp] = (re0,im0,re1,im1)
__global__ __launch_bounds__(256) void k2s_sums(const ushort4* __restrict__ xs4,
                                                float4* __restrict__ sums,
                                                const float* __restrict__ nu,
                                                const float* __restrict__ theta) {
    const int gid = blockIdx.x * 256 + threadIdx.x;   // 8*32*256
    const int hp = gid & 255;
    const int c = (gid >> 8) & (NC - 1);
    const int b = gid >> 13;
    float lre0, lim0, lre1, lim1;
    lam_of(nu, theta, 2 * hp, lre0, lim0);
    lam_of(nu, theta, 2 * hp + 1, lre1, lim1);
    long base = ((long)b * T_LEN + (long)c * CL) * 256 + hp;
    float a0r = 0.f, a0i = 0.f, a1r = 0.f, a1i = 0.f;
#pragma unroll 4
    for (int i = 0; i < CL; ++i) {
        ushort4 v = xs4[base + (long)i * 256];
        float u0r = bf2f(v.x), u0i = bf2f(v.y), u1r = bf2f(v.z), u1i = bf2f(v.w);
        float n0r = fmaf(lre0, a0r, fmaf(-lim0, a0i, u0r));
        float n0i = fmaf(lre0, a0i, fmaf(lim0, a0r, u0i));
        float n1r = fmaf(lre1, a1r, fmaf(-lim1, a1i, u1r));
        float n1i = fmaf(lre1, a1i, fmaf(lim1, a1r, u1i));
        a0r = n0r; a0i = n0i; a1r = n1r; a1i = n1i;
    }
    sums[((long)b * NC + c) * 256 + hp] = make_float4(a0r, a0i, a1r, a1i);
}

// k2b: exclusive scan over chunk sums -> carry (same float4-per-hp layout)
__global__ __launch_bounds__(256) void k2b_carry(const float4* __restrict__ sums,
                                                 float4* __restrict__ carry,
                                                 const float* __restrict__ nu,
                                                 const float* __restrict__ theta) {
    const int gid = blockIdx.x * 256 + threadIdx.x;   // 8*256
    const int hp = gid & 255;
    const int b = gid >> 8;
    float lre0, lim0, lre1, lim1;
    lam_of(nu, theta, 2 * hp, lre0, lim0);
    lam_of(nu, theta, 2 * hp + 1, lre1, lim1);
    // lam^CL via 7 complex squarings (CL = 128 = 2^7)
    float p0r = lre0, p0i = lim0, p1r = lre1, p1i = lim1;
#pragma unroll
    for (int i = 0; i < 7; ++i) {
        float t0 = p0r * p0r - p0i * p0i; p0i = 2.f * p0r * p0i; p0r = t0;
        float t1 = p1r * p1r - p1i * p1i; p1i = 2.f * p1r * p1i; p1r = t1;
    }
    float c0r = 0.f, c0i = 0.f, c1r = 0.f, c1i = 0.f;
    for (int c = 0; c < NC; ++c) {
        long idx = ((long)b * NC + c) * 256 + hp;
        carry[idx] = make_float4(c0r, c0i, c1r, c1i);
        float4 s = sums[idx];
        float t0 = fmaf(p0r, c0r, fmaf(-p0i, c0i, s.x));
        c0i = fmaf(p0r, c0i, fmaf(p0i, c0r, s.y));
        c0r = t0;
        float t1 = fmaf(p1r, c1r, fmaf(-p1i, c1i, s.z));
        c1i = fmaf(p1r, c1i, fmaf(p1i, c1r, s.w));
        c1r = t1;
    }
}

// k2ac: fused local scan starting from carry -> final xs (one R+W pass, f32 state throughout)
__global__ __launch_bounds__(256) void k2ac_scan(ushort4* __restrict__ xs4,
                                                 const float4* __restrict__ carry,
                                                 const float* __restrict__ nu,
                                                 const float* __restrict__ theta) {
    const int gid = blockIdx.x * 256 + threadIdx.x;   // 8*32*256
    const int hp = gid & 255;
    const int c = (gid >> 8) & (NC - 1);
    const int b = gid >> 13;
    float lre0, lim0, lre1, lim1;
    lam_of(nu, theta, 2 * hp, lre0, lim0);
    lam_of(nu, theta, 2 * hp + 1, lre1, lim1);
    float4 cr = carry[((long)b * NC + c) * 256 + hp];
    float a0r = cr.x, a0i = cr.y, a1r = cr.z, a1i = cr.w;
    long base = ((long)b * T_LEN + (long)c * CL) * 256 + hp;
#pragma unroll 4
    for (int i = 0; i < CL; ++i) {
        ushort4 v = xs4[base + (long)i * 256];
        float u0r = bf2f(v.x), u0i = bf2f(v.y), u1r = bf2f(v.z), u1i = bf2f(v.w);
        float n0r = fmaf(lre0, a0r, fmaf(-lim0, a0i, u0r));
        float n0i = fmaf(lre0, a0i, fmaf(lim0, a0r, u0i));
        float n1r = fmaf(lre1, a1r, fmaf(-lim1, a1i, u1r));
        float n1i = fmaf(lre1, a1i, fmaf(lim1, a1r, u1i));
        a0r = n0r; a0i = n0i; a1r = n1r; a1i = n1i;
        ushort4 o;
        o.x = f2bf(a0r); o.y = f2bf(a0i); o.z = f2bf(a1r); o.w = f2bf(a1i);
        xs4[base + (long)i * 256] = o;
    }
}

extern "C" void kernel_launch(void* const* d_in, const int* in_sizes, int n_in,
                              void* d_out, int out_size, void* d_ws, size_t ws_size,
                              hipStream_t stream) {
    const float* x         = (const float*)d_in[0];
    const float* Bre       = (const float*)d_in[1];
    const float* Bim       = (const float*)d_in[2];
    const float* Cre       = (const float*)d_in[3];
    const float* Cim       = (const float*)d_in[4];
    const float* Dv        = (const float*)d_in[5];
    const float* nu        = (const float*)d_in[6];
    const float* theta     = (const float*)d_in[7];
    const float* gamma_log = (const float*)d_in[8];
    float* y = (float*)d_out;

    // ws layout:
    //   [0, 64MB)      xs (bf16 interleaved re,im)
    //   [64MB, 66MB)   region A: BT1 (0.5MB) -> sums (1MB) -> CT (0.5MB)
    //   [66MB, 68MB)   region B: carry (1MB)
    //   [68MB, 84MB)   xb (bf16 x) IF ws_size permits, else xb lives in d_out
    const size_t XS_BYTES  = (size_t)ROWS * H_DIM * 4;
    const size_t REG_BYTES = 2u * 1024 * 1024;
    const size_t XB_BYTES  = (size_t)ROWS * N_DIM * 2;
    unsigned short* xs_us = (unsigned short*)d_ws;
    ushort4* xs4   = (ushort4*)d_ws;
    char* regionA  = (char*)d_ws + XS_BYTES;
    char* regionB  = regionA + REG_BYTES;
    unsigned short* BT1 = (unsigned short*)regionA;
    float4*  sums  = (float4*)regionA;
    unsigned short* CT  = (unsigned short*)regionA;
    float4*  carry = (float4*)regionB;

    const bool xb_in_ws = ws_size >= XS_BYTES + 2 * REG_BYTES + XB_BYTES;
    unsigned short* xb = xb_in_ws ? (unsigned short*)(regionB + REG_BYTES)
                                  : (unsigned short*)d_out;

    conv_x<<<ROWS * N_DIM / 4 / 256, 256, 0, stream>>>((const float4*)x, (ushort4*)xb);
    conv_Bt<<<(N_DIM * H_DIM) / 256, 256, 0, stream>>>(Bre, Bim, BT1);

    // K1: xs = gamma * (u @ Bint)   M=32768 N=1024 K=256   (64x64 tiles, 8192 blocks, 1 chunk)
    gemm_res<0, 256><<<(ROWS / 64) * (1024 / 64), 256, 0, stream>>>(
        xb, BT1, 1024, gamma_log, nullptr, nullptr, xs_us);
    // scan: sums-first (sums overwrites BT1 region; K1 complete by stream order)
    k2s_sums<<<(B_SZ * NC * 256) / 256, 256, 0, stream>>>(xs4, sums, nu, theta);
    k2b_carry<<<(B_SZ * 256) / 256, 256, 0, stream>>>(sums, carry, nu, theta);
    k2ac_scan<<<(B_SZ * NC * 256) / 256, 256, 0, stream>>>(xs4, carry, nu, theta);

    // CT overwrites sums region (dead after k2b)
    conv_Ct<<<(H_DIM * N_DIM) / 256, 256, 0, stream>>>(Cre, Cim, CT);

    // K3: y = Re(xs @ C) + D*u      M=32768 N=256 K=1024   (64x64 tiles, 2048 blocks, 4 chunks)
    gemm_res<1, 1024><<<(ROWS / 64) * (256 / 64), 256, 0, stream>>>(
        xs_us, CT, 256, Dv, x, xb_in_ws ? xb : nullptr, y);
}

// Round 6
// 138.657 us; speedup vs baseline: 1.1527x; 1.1527x over previous
//
#include <hip/hip_runtime.h>

#define B_SZ 8
#define T_LEN 4096
#define N_DIM 256
#define H_DIM 512
#define NC 32
#define CL 128
#define ROWS (B_SZ * T_LEN)

typedef __attribute__((ext_vector_type(4))) float f32x4;
typedef __attribute__((ext_vector_type(8))) short bf16x8;

static __device__ __forceinline__ unsigned short f2bf(float f) {
    unsigned int u = __float_as_uint(f);
    unsigned int r = (u + 0x7FFFu + ((u >> 16) & 1u)) >> 16;
    return (unsigned short)r;
}
static __device__ __forceinline__ float bf2f(unsigned short s) {
    return __uint_as_float(((unsigned int)s) << 16);
}

static __device__ __forceinline__ void lam_of(const float* __restrict__ nu,
                                              const float* __restrict__ theta,
                                              int h, float& lre, float& lim) {
    float r = __expf(-__expf(nu[h]));
    float th = theta[h];
    lre = r * __cosf(th);
    lim = r * __sinf(th);
}

// ---------- conversion kernels ----------
__global__ __launch_bounds__(256) void conv_x(const float4* __restrict__ x, ushort4* __restrict__ xb) {
    int id = blockIdx.x * 256 + threadIdx.x;
    float4 v = x[id];
    ushort4 o;
    o.x = f2bf(v.x); o.y = f2bf(v.y); o.z = f2bf(v.z); o.w = f2bf(v.w);
    xb[id] = o;
}

// BT1[n][k] (1024 x 256): n=2h -> Bre[k][h], n=2h+1 -> Bim[k][h]
__global__ __launch_bounds__(256) void conv_Bt(const float* __restrict__ Bre,
                                               const float* __restrict__ Bim,
                                               unsigned short* __restrict__ BT1) {
    int id = blockIdx.x * 256 + threadIdx.x;           // id = k*512 + h
    int k = id >> 9, h = id & 511;
    BT1[(long)(2 * h) * 256 + k]     = f2bf(Bre[id]);
    BT1[(long)(2 * h + 1) * 256 + k] = f2bf(Bim[id]);
}

// CT[n][k] (256 x 1024): k=2h -> Cre[h][n], k=2h+1 -> -Cim[h][n]
__global__ __launch_bounds__(256) void conv_Ct(const float* __restrict__ Cre,
                                               const float* __restrict__ Cim,
                                               unsigned short* __restrict__ CT) {
    int id = blockIdx.x * 256 + threadIdx.x;           // id = h*256 + nn
    int h = id >> 8, nn = id & 255;
    CT[(long)nn * 1024 + 2 * h]     = f2bf(Cre[id]);
    CT[(long)nn * 1024 + 2 * h + 1] = f2bf(-Cim[id]);
}

// ---------- phase-interleaved MFMA GEMM (T2+T3+T4+T5 stack) ----------
// out = A(MxK) @ Bt(NxK)^T.  256xBNt tile, 8 waves (2M x 4N), per-wave
// 128 x (BNt/4).  BK=32, 3 LDS K-tile buffers, prefetch distance 2,
// boundary vmcnt(S) never 0 mid-loop.  2 phases per K-tile, each:
//   {issue stage glls for tile kt+2} {ds_read subtile} barrier
//   setprio(1) 16(or 8) MFMA setprio(0) barrier
// LDS swizzle = R1's HW-verified pair (0 conflicts): gll writes linearly,
// per-lane GLOBAL source k-seg permuted 8*((l&3)^((l>>3)&3)); read XOR
// 16*((lane>>4)^((lane>>1)&3)).  Swapped-operand MFMA (R4-verified):
// lane holds row=lane&15, cols=(lane>>4)*4+r -> vector epilogue stores.
// MODE 0: K1 (scale by gamma[col/2], store bf16)
// MODE 1: K3 (add D[col]*u, store f32); u from e1b (bf16) if non-null else e1
template <int MODE, int BNt, int KC>
__global__ __launch_bounds__(512, 2) void gemm_8ph(const unsigned short* __restrict__ A,
                                                   const unsigned short* __restrict__ Bt,
                                                   int N,
                                                   const float* __restrict__ e0,
                                                   const float* __restrict__ e1,
                                                   const unsigned short* __restrict__ e1b,
                                                   void* __restrict__ out) {
    constexpr int BMt = 256;
    constexpr int NR = BNt / 64;        // frags per wave in N: 4 (BN=256) / 2 (BN=128)
    constexpr int GA = BMt / 128;       // A gll units (1KB) per wave per K-tile = 2
    constexpr int GB = BNt / 128;       // B gll units per wave per K-tile = 2 / 1
    constexpr int S  = GA + GB;         // glls per wave per K-tile
    constexpr int NT = KC / 32;

    __shared__ unsigned short As[3][BMt * 32];   // 3 x 16 KB
    __shared__ unsigned short Bs[3][BNt * 32];   // 3 x 16/8 KB

    const int tid  = threadIdx.x;
    const int lane = tid & 63;
    const int wave = tid >> 6;
    const int wr = wave >> 2;           // 0..1  (M half)
    const int wc = wave & 3;            // 0..3  (N quarter)

    // XCD-aware swizzle (grid % 8 == 0 for both instantiations)
    const int nwg = (int)gridDim.x;
    const int cpx = nwg >> 3;
    const int bid = (int)blockIdx.x;
    const int tile = (bid & 7) * cpx + (bid >> 3);

    const int nTilesN = N / BNt;
    const long tileM = (long)(tile / nTilesN) * BMt;
    const long tileN = (long)(tile % nTilesN) * BNt;

    // staging: unit c (1KB) covers rows [c*16,(c+1)*16); lane l -> row
    // c*16+(l>>2), slot l&3; source k-seg pre-swizzled (write side of T2).
    const int sg = 8 * ((lane & 3) ^ ((lane >> 3) & 3));    // ushorts
    const int srow = lane >> 2;
    const unsigned short* Ag = A + (tileM + srow) * (long)KC + sg;
    const unsigned short* Bg = Bt + (tileN + srow) * (long)KC + sg;

    auto stageA = [&](int buf, int kt) {
        const int k0 = kt * 32;
#pragma unroll
        for (int i = 0; i < GA; ++i) {
            const int c = wave * GA + i;
            __builtin_amdgcn_global_load_lds(
                (const __attribute__((address_space(1))) unsigned int*)(Ag + (long)c * 16 * KC + k0),
                (__attribute__((address_space(3))) unsigned int*)(&As[buf][c * 512]),
                16, 0, 0);
        }
    };
    auto stageB = [&](int buf, int kt) {
        const int k0 = kt * 32;
#pragma unroll
        for (int i = 0; i < GB; ++i) {
            const int c = wave * GB + i;
            __builtin_amdgcn_global_load_lds(
                (const __attribute__((address_space(1))) unsigned int*)(Bg + (long)c * 16 * KC + k0),
                (__attribute__((address_space(3))) unsigned int*)(&Bs[buf][c * 512]),
                16, 0, 0);
        }
    };

    // read-side swizzle (matches write side; R1-verified, 0 conflicts)
    const int rdx = 16 * ((lane >> 4) ^ ((lane >> 1) & 3));
    const int fr = lane & 15;

    f32x4 acc[8][NR] = {};

    stageA(0, 0); stageB(0, 0);
    stageA(1, 1); stageB(1, 1);
    if constexpr (S == 4) asm volatile("s_waitcnt vmcnt(4)" ::: "memory");
    else                  asm volatile("s_waitcnt vmcnt(3)" ::: "memory");
    __builtin_amdgcn_s_barrier();

    int cur = 0, pf = 2;
    for (int kt = 0; kt < NT; ++kt) {
        const bool more = (kt + 2 < NT);
        // ---- phase A: stage A(kt+2) | read A-half0 + B | MFMA m0..3 ----
        if (more) stageA(pf, kt + 2);
        bf16x8 a0[4], bfr[NR];
#pragma unroll
        for (int m = 0; m < 4; ++m)
            a0[m] = *(const bf16x8*)((const char*)As[cur] + (wr * 128 + m * 16 + fr) * 64 + rdx);
#pragma unroll
        for (int n = 0; n < NR; ++n)
            bfr[n] = *(const bf16x8*)((const char*)Bs[cur] + (wc * (NR * 16) + n * 16 + fr) * 64 + rdx);
        asm volatile("" ::: "memory");
        __builtin_amdgcn_s_barrier();
        __builtin_amdgcn_s_setprio(1);
#pragma unroll
        for (int m = 0; m < 4; ++m)
#pragma unroll
            for (int n = 0; n < NR; ++n)
                acc[m][n] = __builtin_amdgcn_mfma_f32_16x16x32_bf16(bfr[n], a0[m], acc[m][n], 0, 0, 0);
        __builtin_amdgcn_s_setprio(0);
        asm volatile("" ::: "memory");
        __builtin_amdgcn_s_barrier();
        // ---- phase B: stage B(kt+2) | read A-half1 | MFMA m4..7 ----
        if (more) stageB(pf, kt + 2);
        bf16x8 a1[4];
#pragma unroll
        for (int m = 0; m < 4; ++m)
            a1[m] = *(const bf16x8*)((const char*)As[cur] + (wr * 128 + (m + 4) * 16 + fr) * 64 + rdx);
        asm volatile("" ::: "memory");
        __builtin_amdgcn_s_barrier();
        __builtin_amdgcn_s_setprio(1);
#pragma unroll
        for (int m = 0; m < 4; ++m)
#pragma unroll
            for (int n = 0; n < NR; ++n)
                acc[m + 4][n] = __builtin_amdgcn_mfma_f32_16x16x32_bf16(bfr[n], a1[m], acc[m + 4][n], 0, 0, 0);
        __builtin_amdgcn_s_setprio(0);
        asm volatile("" ::: "memory");
        if (kt + 1 < NT) {
            // boundary: tile kt+1 must be resident; allow tile kt+2's S glls
            // to stay in flight (counted vmcnt, never 0 while more tiles fly)
            if (more) {
                if constexpr (S == 4) asm volatile("s_waitcnt vmcnt(4)" ::: "memory");
                else                  asm volatile("s_waitcnt vmcnt(3)" ::: "memory");
            } else {
                asm volatile("s_waitcnt vmcnt(0)" ::: "memory");
            }
            __builtin_amdgcn_s_barrier();
        }
        cur = (cur == 2) ? 0 : cur + 1;
        pf  = (pf == 2) ? 0 : pf + 1;
    }

    // ---- epilogue: swapped-operand layout -> vectorized stores (R4-verified) ----
    const int fs = lane >> 4;
    if constexpr (MODE == 0) {
        unsigned short* o = (unsigned short*)out;
        float g0v[NR], g1v[NR];
#pragma unroll
        for (int n = 0; n < NR; ++n) {
            const int col0 = (int)tileN + wc * (NR * 16) + n * 16 + fs * 4;
            g0v[n] = __expf(e0[col0 >> 1]);
            g1v[n] = __expf(e0[(col0 >> 1) + 1]);
        }
#pragma unroll
        for (int m = 0; m < 8; ++m) {
            const long grow = tileM + wr * 128 + m * 16 + fr;
#pragma unroll
            for (int n = 0; n < NR; ++n) {
                const int col0 = (int)tileN + wc * (NR * 16) + n * 16 + fs * 4;
                ushort4 pk;
                pk.x = f2bf(acc[m][n][0] * g0v[n]);
                pk.y = f2bf(acc[m][n][1] * g0v[n]);
                pk.z = f2bf(acc[m][n][2] * g1v[n]);
                pk.w = f2bf(acc[m][n][3] * g1v[n]);
                *(ushort4*)(o + grow * N + col0) = pk;
            }
        }
    } else {
        float* o = (float*)out;
        float4 dvv[NR];
#pragma unroll
        for (int n = 0; n < NR; ++n) {
            const int col0 = (int)tileN + wc * (NR * 16) + n * 16 + fs * 4;
            dvv[n] = *(const float4*)(e0 + col0);
        }
#pragma unroll
        for (int m = 0; m < 8; ++m) {
            const long grow = tileM + wr * 128 + m * 16 + fr;
#pragma unroll
            for (int n = 0; n < NR; ++n) {
                const int col0 = (int)tileN + wc * (NR * 16) + n * 16 + fs * 4;
                const long idx = grow * N + col0;
                float u0, u1, u2, u3;
                if (e1b) {
                    ushort4 ub = *(const ushort4*)(e1b + idx);
                    u0 = bf2f(ub.x); u1 = bf2f(ub.y); u2 = bf2f(ub.z); u3 = bf2f(ub.w);
                } else {
                    float4 uf = *(const float4*)(e1 + idx);
                    u0 = uf.x; u1 = uf.y; u2 = uf.z; u3 = uf.w;
                }
                float4 st;
                st.x = acc[m][n][0] + dvv[n].x * u0;
                st.y = acc[m][n][1] + dvv[n].y * u1;
                st.z = acc[m][n][2] + dvv[n].z * u2;
                st.w = acc[m][n][3] + dvv[n].w * u3;
                *(float4*)(o + idx) = st;
            }
        }
    }
}

// ---------- scan: sums-first, then fused local-scan-from-carry ----------
// thread handles 2 complex h's (ushort4 = 8B loads, 512B/wave coalesced)

// k2s: read-only chunk sums. sums[(b*NC+c)*256+hp] = (re0,im0,re1,im1)
__global__ __launch_bounds__(256) void k2s_sums(const ushort4* __restrict__ xs4,
                                                float4* __restrict__ sums,
                                                const float* __restrict__ nu,
                                                const float* __restrict__ theta) {
    const int gid = blockIdx.x * 256 + threadIdx.x;   // 8*32*256
    const int hp = gid & 255;
    const int c = (gid >> 8) & (NC - 1);
    const int b = gid >> 13;
    float lre0, lim0, lre1, lim1;
    lam_of(nu, theta, 2 * hp, lre0, lim0);
    lam_of(nu, theta, 2 * hp + 1, lre1, lim1);
    long base = ((long)b * T_LEN + (long)c * CL) * 256 + hp;
    float a0r = 0.f, a0i = 0.f, a1r = 0.f, a1i = 0.f;
#pragma unroll 4
    for (int i = 0; i < CL; ++i) {
        ushort4 v = xs4[base + (long)i * 256];
        float u0r = bf2f(v.x), u0i = bf2f(v.y), u1r = bf2f(v.z), u1i = bf2f(v.w);
        float n0r = fmaf(lre0, a0r, fmaf(-lim0, a0i, u0r));
        float n0i = fmaf(lre0, a0i, fmaf(lim0, a0r, u0i));
        float n1r = fmaf(lre1, a1r, fmaf(-lim1, a1i, u1r));
        float n1i = fmaf(lre1, a1i, fmaf(lim1, a1r, u1i));
        a0r = n0r; a0i = n0i; a1r = n1r; a1i = n1i;
    }
    sums[((long)b * NC + c) * 256 + hp] = make_float4(a0r, a0i, a1r, a1i);
}

// k2b: exclusive scan over chunk sums -> carry (same float4-per-hp layout)
__global__ __launch_bounds__(256) void k2b_carry(const float4* __restrict__ sums,
                                                 float4* __restrict__ carry,
                                                 const float* __restrict__ nu,
                                                 const float* __restrict__ theta) {
    const int gid = blockIdx.x * 256 + threadIdx.x;   // 8*256
    const int hp = gid & 255;
    const int b = gid >> 8;
    float lre0, lim0, lre1, lim1;
    lam_of(nu, theta, 2 * hp, lre0, lim0);
    lam_of(nu, theta, 2 * hp + 1, lre1, lim1);
    // lam^CL via 7 complex squarings (CL = 128 = 2^7)
    float p0r = lre0, p0i = lim0, p1r = lre1, p1i = lim1;
#pragma unroll
    for (int i = 0; i < 7; ++i) {
        float t0 = p0r * p0r - p0i * p0i; p0i = 2.f * p0r * p0i; p0r = t0;
        float t1 = p1r * p1r - p1i * p1i; p1i = 2.f * p1r * p1i; p1r = t1;
    }
    float c0r = 0.f, c0i = 0.f, c1r = 0.f, c1i = 0.f;
    for (int c = 0; c < NC; ++c) {
        long idx = ((long)b * NC + c) * 256 + hp;
        carry[idx] = make_float4(c0r, c0i, c1r, c1i);
        float4 s = sums[idx];
        float t0 = fmaf(p0r, c0r, fmaf(-p0i, c0i, s.x));
        c0i = fmaf(p0r, c0i, fmaf(p0i, c0r, s.y));
        c0r = t0;
        float t1 = fmaf(p1r, c1r, fmaf(-p1i, c1i, s.z));
        c1i = fmaf(p1r, c1i, fmaf(p1i, c1r, s.w));
        c1r = t1;
    }
}

// k2ac: fused local scan starting from carry -> final xs (one R+W pass, f32 state throughout)
__global__ __launch_bounds__(256) void k2ac_scan(ushort4* __restrict__ xs4,
                                                 const float4* __restrict__ carry,
                                                 const float* __restrict__ nu,
                                                 const float* __restrict__ theta) {
    const int gid = blockIdx.x * 256 + threadIdx.x;   // 8*32*256
    const int hp = gid & 255;
    const int c = (gid >> 8) & (NC - 1);
    const int b = gid >> 13;
    float lre0, lim0, lre1, lim1;
    lam_of(nu, theta, 2 * hp, lre0, lim0);
    lam_of(nu, theta, 2 * hp + 1, lre1, lim1);
    float4 cr = carry[((long)b * NC + c) * 256 + hp];
    float a0r = cr.x, a0i = cr.y, a1r = cr.z, a1i = cr.w;
    long base = ((long)b * T_LEN + (long)c * CL) * 256 + hp;
#pragma unroll 4
    for (int i = 0; i < CL; ++i) {
        ushort4 v = xs4[base + (long)i * 256];
        float u0r = bf2f(v.x), u0i = bf2f(v.y), u1r = bf2f(v.z), u1i = bf2f(v.w);
        float n0r = fmaf(lre0, a0r, fmaf(-lim0, a0i, u0r));
        float n0i = fmaf(lre0, a0i, fmaf(lim0, a0r, u0i));
        float n1r = fmaf(lre1, a1r, fmaf(-lim1, a1i, u1r));
        float n1i = fmaf(lre1, a1i, fmaf(lim1, a1r, u1i));
        a0r = n0r; a0i = n0i; a1r = n1r; a1i = n1i;
        ushort4 o;
        o.x = f2bf(a0r); o.y = f2bf(a0i); o.z = f2bf(a1r); o.w = f2bf(a1i);
        xs4[base + (long)i * 256] = o;
    }
}

extern "C" void kernel_launch(void* const* d_in, const int* in_sizes, int n_in,
                              void* d_out, int out_size, void* d_ws, size_t ws_size,
                              hipStream_t stream) {
    const float* x         = (const float*)d_in[0];
    const float* Bre       = (const float*)d_in[1];
    const float* Bim       = (const float*)d_in[2];
    const float* Cre       = (const float*)d_in[3];
    const float* Cim       = (const float*)d_in[4];
    const float* Dv        = (const float*)d_in[5];
    const float* nu        = (const float*)d_in[6];
    const float* theta     = (const float*)d_in[7];
    const float* gamma_log = (const float*)d_in[8];
    float* y = (float*)d_out;

    // ws layout:
    //   [0, 64MB)      xs (bf16 interleaved re,im)
    //   [64MB, 66MB)   region A: BT1 (0.5MB) -> sums (1MB) -> CT (0.5MB)
    //   [66MB, 68MB)   region B: carry (1MB)
    //   [68MB, 84MB)   xb (bf16 x) IF ws_size permits, else xb lives in d_out
    const size_t XS_BYTES  = (size_t)ROWS * H_DIM * 4;
    const size_t REG_BYTES = 2u * 1024 * 1024;
    const size_t XB_BYTES  = (size_t)ROWS * N_DIM * 2;
    unsigned short* xs_us = (unsigned short*)d_ws;
    ushort4* xs4   = (ushort4*)d_ws;
    char* regionA  = (char*)d_ws + XS_BYTES;
    char* regionB  = regionA + REG_BYTES;
    unsigned short* BT1 = (unsigned short*)regionA;
    float4*  sums  = (float4*)regionA;
    unsigned short* CT  = (unsigned short*)regionA;
    float4*  carry = (float4*)regionB;

    const bool xb_in_ws = ws_size >= XS_BYTES + 2 * REG_BYTES + XB_BYTES;
    unsigned short* xb = xb_in_ws ? (unsigned short*)(regionB + REG_BYTES)
                                  : (unsigned short*)d_out;

    conv_x<<<ROWS * N_DIM / 4 / 256, 256, 0, stream>>>((const float4*)x, (ushort4*)xb);
    conv_Bt<<<(N_DIM * H_DIM) / 256, 256, 0, stream>>>(Bre, Bim, BT1);

    // K1: xs = gamma * (u @ Bint)   M=32768 N=1024 K=256   (256x256, 512 blocks)
    gemm_8ph<0, 256, 256><<<512, 512, 0, stream>>>(xb, BT1, 1024,
                                                   gamma_log, nullptr, nullptr, xs_us);
    // scan: sums-first (sums overwrites BT1 region; K1 complete by stream order)
    k2s_sums<<<(B_SZ * NC * 256) / 256, 256, 0, stream>>>(xs4, sums, nu, theta);
    k2b_carry<<<(B_SZ * 256) / 256, 256, 0, stream>>>(sums, carry, nu, theta);
    k2ac_scan<<<(B_SZ * NC * 256) / 256, 256, 0, stream>>>(xs4, carry, nu, theta);

    // CT overwrites sums region (dead after k2b)
    conv_Ct<<<(H_DIM * N_DIM) / 256, 256, 0, stream>>>(Cre, Cim, CT);

    // K3: y = Re(xs @ C) + D*u      M=32768 N=256 K=1024   (256x128, 256 blocks)
    gemm_8ph<1, 128, 1024><<<256, 512, 0, stream>>>(xs_us, CT, 256,
                                                    Dv, x, xb_in_ws ? xb : nullptr, y);
}

// Round 7
// 121.178 us; speedup vs baseline: 1.3190x; 1.1442x over previous
//
#include <hip/hip_runtime.h>

#define B_SZ 8
#define T_LEN 4096
#define N_DIM 256
#define H_DIM 512
#define NC 32
#define CL 128
#define ROWS (B_SZ * T_LEN)

#define BM 128
#define BN 128
#define BKg 32

typedef __attribute__((ext_vector_type(4))) float f32x4;
typedef __attribute__((ext_vector_type(8))) short bf16x8;

static __device__ __forceinline__ unsigned short f2bf(float f) {
    unsigned int u = __float_as_uint(f);
    unsigned int r = (u + 0x7FFFu + ((u >> 16) & 1u)) >> 16;
    return (unsigned short)r;
}
static __device__ __forceinline__ float bf2f(unsigned short s) {
    return __uint_as_float(((unsigned int)s) << 16);
}

static __device__ __forceinline__ void lam_of(const float* __restrict__ nu,
                                              const float* __restrict__ theta,
                                              int h, float& lre, float& lim) {
    float r = __expf(-__expf(nu[h]));
    float th = theta[h];
    lre = r * __cosf(th);
    lim = r * __sinf(th);
}

// weighted 4-row partial of the chunk sum for head h:
//   out = sum_m lam^(pb-16m) * (ur[m] + i*ui[m]),  lam = exp(-e^nu[h] + i*theta[h])
// lam^p computed in closed form: exp(-p*e^nu)*(cos p*theta, sin p*theta);
// m=2..0 via a lam^16 ladder (3 complex mults instead of 9 transcendentals).
static __device__ __forceinline__ void csum4(const float* __restrict__ nu,
                                             const float* __restrict__ theta,
                                             int h, int pb,
                                             const float* ur, const float* ui,
                                             float& outr, float& outi) {
    const float e  = __expf(nu[h]);
    const float th = theta[h];
    const float p3 = (float)(pb - 48);
    const float r3 = __expf(-p3 * e);
    float w_r = r3 * __cosf(p3 * th);
    float w_i = r3 * __sinf(p3 * th);
    const float r16 = __expf(-16.f * e);
    const float l_r = r16 * __cosf(16.f * th);
    const float l_i = r16 * __sinf(16.f * th);
    float sr = w_r * ur[3] - w_i * ui[3];
    float si = w_r * ui[3] + w_i * ur[3];
#pragma unroll
    for (int m = 2; m >= 0; --m) {
        const float nwr = w_r * l_r - w_i * l_i;
        const float nwi = w_r * l_i + w_i * l_r;
        w_r = nwr; w_i = nwi;
        sr += w_r * ur[m] - w_i * ui[m];
        si += w_r * ui[m] + w_i * ur[m];
    }
    outr = sr; outi = si;
}

// ---------- conversion kernels ----------
__global__ __launch_bounds__(256) void conv_x(const float4* __restrict__ x, ushort4* __restrict__ xb) {
    int id = blockIdx.x * 256 + threadIdx.x;
    float4 v = x[id];
    ushort4 o;
    o.x = f2bf(v.x); o.y = f2bf(v.y); o.z = f2bf(v.z); o.w = f2bf(v.w);
    xb[id] = o;
}

// BT1[n][k] (1024 x 256): n=2h -> Bre[k][h], n=2h+1 -> Bim[k][h]
__global__ __launch_bounds__(256) void conv_Bt(const float* __restrict__ Bre,
                                               const float* __restrict__ Bim,
                                               unsigned short* __restrict__ BT1) {
    int id = blockIdx.x * 256 + threadIdx.x;           // id = k*512 + h
    int k = id >> 9, h = id & 511;
    BT1[(long)(2 * h) * 256 + k]     = f2bf(Bre[id]);
    BT1[(long)(2 * h + 1) * 256 + k] = f2bf(Bim[id]);
}

// CT[n][k] (256 x 1024): k=2h -> Cre[h][n], k=2h+1 -> -Cim[h][n]
__global__ __launch_bounds__(256) void conv_Ct(const float* __restrict__ Cre,
                                               const float* __restrict__ Cim,
                                               unsigned short* __restrict__ CT) {
    int id = blockIdx.x * 256 + threadIdx.x;           // id = h*256 + nn
    int h = id >> 8, nn = id & 255;
    CT[(long)nn * 1024 + 2 * h]     = f2bf(Cre[id]);
    CT[(long)nn * 1024 + 2 * h + 1] = f2bf(-Cim[id]);
}

// ---------- MFMA GEMM: out = A(MxK) @ Bt(NxK)^T, bf16 in, f32 acc ----------
// K-loop: R1/R4 structure (best measured): 3 LDS buffers, depth-2 counted-
// vmcnt pipeline, RAW s_barrier, write-side XOR swizzle via pre-permuted
// global source + matching read-side XOR (0 bank conflicts, HW-verified).
// Swapped-operand MFMA (R4-verified): lane holds row=lane&15,
// cols=(lane>>4)*4+r -> vectorized line-coalesced epilogue stores.
// R7: MODE 0 additionally FUSES the scan's chunk-sum pass (k2s): the BM=128
// tile is exactly one scan chunk (CL=128, aligned), so the weighted sum
// sum_i lam^(127-i) u_i is computed from the f32 accumulators in-register
// (per-lane 4-row partial -> shfl_xor over the 16-lane fr-group -> cross-
// wave add via 1KB of dead LDS -> one float4 store per h-pair).  This
// deletes k2s's full 64MB re-read of xs.
// MODE 0: K1 epilogue (scale by gamma, store bf16 xs, emit chunk sums)
// MODE 1: K3 epilogue (add D[col]*u[row][col], store f32); u from e1b (bf16) if non-null else e1 (f32)
template <int MODE>
__global__ __launch_bounds__(256) void gemm_mfma(const unsigned short* __restrict__ A,
                                                 const unsigned short* __restrict__ Bt,
                                                 int M, int N, int K,
                                                 const float* __restrict__ e0,
                                                 const float* __restrict__ e1,
                                                 const unsigned short* __restrict__ e1b,
                                                 const float* __restrict__ nu,
                                                 const float* __restrict__ theta,
                                                 float4* __restrict__ sums,
                                                 void* __restrict__ out) {
    __shared__ __align__(16) unsigned short As[3][BM * BKg];   // 3 x 8 KB
    __shared__ __align__(16) unsigned short Bs[3][BN * BKg];   // 3 x 8 KB
    const int tid = threadIdx.x;
    const int lane = tid & 63;
    const int wave = tid >> 6;
    const int wr = wave >> 1, wc = wave & 1;

    // XCD-aware swizzle (grid % 8 == 0 for both instantiations)
    const int nwg = (int)gridDim.x;
    const int cpx = nwg >> 3;
    const int bid = (int)blockIdx.x;
    const int tile = (bid & 7) * cpx + (bid >> 3);

    const int nTilesN = N / BN;
    const long tileM = (long)(tile / nTilesN) * BM;
    const long tileN = (long)(tile % nTilesN) * BN;

    // staging geometry (per-lane constants).  LDS row r = c*16 + (lane>>2),
    // LDS slot = lane&3 (16B units).  Source k-segment = slot ^ ((r>>1)&3),
    // and (r>>1)&3 == (lane>>3)&3 here.
    const int rsub = lane >> 2;
    const int sg = 8 * ((lane & 3) ^ ((lane >> 3) & 3));    // swizzled k-offset (ushorts)
    const unsigned short* Abase = A + tileM * (long)K + sg;
    const unsigned short* Bbase = Bt + tileN * (long)K + sg;

    auto stage = [&](int buf, int k0) {
#pragma unroll
        for (int cc = 0; cc < 2; ++cc) {
            const int c = wave + cc * 4;
            const int row = c * 16 + rsub;
            const unsigned short* ga = Abase + (long)row * K + k0;
            __builtin_amdgcn_global_load_lds((const __attribute__((address_space(1))) unsigned int*)ga,
                                             (__attribute__((address_space(3))) unsigned int*)(As[buf] + c * 512),
                                             16, 0, 0);
            const unsigned short* gb = Bbase + (long)row * K + k0;
            __builtin_amdgcn_global_load_lds((const __attribute__((address_space(1))) unsigned int*)gb,
                                             (__attribute__((address_space(3))) unsigned int*)(Bs[buf] + c * 512),
                                             16, 0, 0);
        }
    };

    // read-side swizzle: want global k-segment (lane>>4); stored at slot
    // (lane>>4) ^ ((row>>1)&3), and row bits 1-2 == lane bits 1-2.
    const int rdA = 16 * ((lane >> 4) ^ ((lane >> 1) & 3));  // byte offset in row

    f32x4 acc[4][4] = {};
    const int nt = K / BKg;

    stage(0, 0);
    stage(1, BKg);

    int cur = 0, pf = 2;
    for (int t = 0; t < nt; ++t) {
        if (t + 2 < nt) {
            stage(pf, (t + 2) * BKg);
            asm volatile("s_waitcnt vmcnt(8)" ::: "memory");   // tile t's 4 glls done
        } else if (t + 1 < nt) {
            asm volatile("s_waitcnt vmcnt(4)" ::: "memory");
        } else {
            asm volatile("s_waitcnt vmcnt(0)" ::: "memory");
        }
        __builtin_amdgcn_s_barrier();                          // all waves: tile t resident
        asm volatile("" ::: "memory");

        bf16x8 af[4], bfr[4];
#pragma unroll
        for (int m = 0; m < 4; ++m) {
            const int row = wr * 64 + m * 16 + (lane & 15);
            af[m] = *(const bf16x8*)((const char*)As[cur] + row * 64 + rdA);
        }
#pragma unroll
        for (int n = 0; n < 4; ++n) {
            const int row = wc * 64 + n * 16 + (lane & 15);
            bfr[n] = *(const bf16x8*)((const char*)Bs[cur] + row * 64 + rdA);
        }
        // swapped operands: acc[m][n] holds the TRANSPOSED 16x16 tile:
        // out row = lane&15, out cols = (lane>>4)*4 + r  (r = reg index)
#pragma unroll
        for (int m = 0; m < 4; ++m)
#pragma unroll
            for (int n = 0; n < 4; ++n)
                acc[m][n] = __builtin_amdgcn_mfma_f32_16x16x32_bf16(bfr[n], af[m], acc[m][n], 0, 0, 0);

        asm volatile("" ::: "memory");
        __builtin_amdgcn_s_barrier();                          // reads of buf cur retired
        asm volatile("" ::: "memory");

        cur = (cur == 2) ? 0 : cur + 1;
        pf = (pf == 2) ? 0 : pf + 1;
    }

    const int fr = lane & 15;
    const int fs = lane >> 4;
    if constexpr (MODE == 0) {
        unsigned short* o = (unsigned short*)out;
        float s_r0[4], s_i0[4], s_r1[4], s_i1[4];
        const int pb = 127 - wr * 64 - fr;                     // weight exponent base
#pragma unroll
        for (int n = 0; n < 4; ++n) {
            const int col0 = (int)tileN + wc * 64 + n * 16 + fs * 4;   // multiple of 4
            const int h0 = col0 >> 1;                                  // cols (col0,col0+1)->h0, (+2,+3)->h0+1
            const float g0 = __expf(e0[h0]);
            const float g1 = __expf(e0[h0 + 1]);
            float ur0[4], ui0[4], ur1[4], ui1[4];
#pragma unroll
            for (int m = 0; m < 4; ++m) {
                const long grow = tileM + wr * 64 + m * 16 + fr;
                const float v0 = acc[m][n][0] * g0;
                const float v1 = acc[m][n][1] * g0;
                const float v2 = acc[m][n][2] * g1;
                const float v3 = acc[m][n][3] * g1;
                ushort4 pk;
                pk.x = f2bf(v0); pk.y = f2bf(v1); pk.z = f2bf(v2); pk.w = f2bf(v3);
                *(ushort4*)(o + grow * N + col0) = pk;                 // 8B store, line-coalesced
                ur0[m] = v0; ui0[m] = v1; ur1[m] = v2; ui1[m] = v3;
            }
            // fused k2s: per-lane weighted partial over this lane's 4 rows
            csum4(nu, theta, h0,     pb, ur0, ui0, s_r0[n], s_i0[n]);
            csum4(nu, theta, h0 + 1, pb, ur1, ui1, s_r1[n], s_i1[n]);
        }
        // reduce over the 16-lane fr-group (lanes fs*16 .. fs*16+15)
#pragma unroll
        for (int n = 0; n < 4; ++n) {
#pragma unroll
            for (int st = 1; st < 16; st <<= 1) {
                s_r0[n] += __shfl_xor(s_r0[n], st);
                s_i0[n] += __shfl_xor(s_i0[n], st);
                s_r1[n] += __shfl_xor(s_r1[n], st);
                s_i1[n] += __shfl_xor(s_i1[n], st);
            }
        }
        __syncthreads();                        // K-loop LDS dead -> reuse As as reduce buffer
        float4* red = (float4*)As;              // 64 slots x 16B = 1 KB
        if (fr == 0) {
#pragma unroll
            for (int n = 0; n < 4; ++n)
                red[wr * 32 + wc * 16 + n * 4 + fs] = make_float4(s_r0[n], s_i0[n], s_r1[n], s_i1[n]);
        }
        __syncthreads();
        if (tid < 32) {
            float4 a = red[tid], b2 = red[32 + tid];
            // sums[(b*NC+c)*256 + hp]; (b*NC+c) == tileM/128, hp == tileN/4 + slot
            sums[(long)(tileM >> 7) * 256 + (tileN >> 2) + tid] =
                make_float4(a.x + b2.x, a.y + b2.y, a.z + b2.z, a.w + b2.w);
        }
    } else {
        float* o = (float*)out;
#pragma unroll
        for (int n = 0; n < 4; ++n) {
            const int col0 = (int)tileN + wc * 64 + n * 16 + fs * 4;   // multiple of 4
            const float4 dv = *(const float4*)(e0 + col0);
#pragma unroll
            for (int m = 0; m < 4; ++m) {
                const long grow = tileM + wr * 64 + m * 16 + fr;
                const long idx = grow * N + col0;
                float u0, u1, u2, u3;
                if (e1b) {
                    ushort4 ub = *(const ushort4*)(e1b + idx);
                    u0 = bf2f(ub.x); u1 = bf2f(ub.y); u2 = bf2f(ub.z); u3 = bf2f(ub.w);
                } else {
                    float4 uf = *(const float4*)(e1 + idx);
                    u0 = uf.x; u1 = uf.y; u2 = uf.z; u3 = uf.w;
                }
                float4 st;
                st.x = acc[m][n][0] + dv.x * u0;
                st.y = acc[m][n][1] + dv.y * u1;
                st.z = acc[m][n][2] + dv.z * u2;
                st.w = acc[m][n][3] + dv.w * u3;
                *(float4*)(o + idx) = st;                              // 16B store, line-coalesced
            }
        }
    }
}

// ---------- scan: chunk sums fused into K1; k2b carries, k2ac local scan ----------

// k2b: exclusive scan over chunk sums -> carry (float4-per-hp layout)
__global__ __launch_bounds__(256) void k2b_carry(const float4* __restrict__ sums,
                                                 float4* __restrict__ carry,
                                                 const float* __restrict__ nu,
                                                 const float* __restrict__ theta) {
    const int gid = blockIdx.x * 256 + threadIdx.x;   // 8*256
    const int hp = gid & 255;
    const int b = gid >> 8;
    float lre0, lim0, lre1, lim1;
    lam_of(nu, theta, 2 * hp, lre0, lim0);
    lam_of(nu, theta, 2 * hp + 1, lre1, lim1);
    // lam^CL via 7 complex squarings (CL = 128 = 2^7)
    float p0r = lre0, p0i = lim0, p1r = lre1, p1i = lim1;
#pragma unroll
    for (int i = 0; i < 7; ++i) {
        float t0 = p0r * p0r - p0i * p0i; p0i = 2.f * p0r * p0i; p0r = t0;
        float t1 = p1r * p1r - p1i * p1i; p1i = 2.f * p1r * p1i; p1r = t1;
    }
    float c0r = 0.f, c0i = 0.f, c1r = 0.f, c1i = 0.f;
#pragma unroll
    for (int c = 0; c < NC; ++c) {
        long idx = ((long)b * NC + c) * 256 + hp;
        carry[idx] = make_float4(c0r, c0i, c1r, c1i);
        float4 s = sums[idx];
        float t0 = fmaf(p0r, c0r, fmaf(-p0i, c0i, s.x));
        c0i = fmaf(p0r, c0i, fmaf(p0i, c0r, s.y));
        c0r = t0;
        float t1 = fmaf(p1r, c1r, fmaf(-p1i, c1i, s.z));
        c1i = fmaf(p1r, c1i, fmaf(p1i, c1r, s.w));
        c1r = t1;
    }
}

// k2ac: fused local scan starting from carry -> final xs (one R+W pass, f32 state throughout)
__global__ __launch_bounds__(256) void k2ac_scan(ushort4* __restrict__ xs4,
                                                 const float4* __restrict__ carry,
                                                 const float* __restrict__ nu,
                                                 const float* __restrict__ theta) {
    const int gid = blockIdx.x * 256 + threadIdx.x;   // 8*32*256
    const int hp = gid & 255;
    const int c = (gid >> 8) & (NC - 1);
    const int b = gid >> 13;
    float lre0, lim0, lre1, lim1;
    lam_of(nu, theta, 2 * hp, lre0, lim0);
    lam_of(nu, theta, 2 * hp + 1, lre1, lim1);
    float4 cr = carry[((long)b * NC + c) * 256 + hp];
    float a0r = cr.x, a0i = cr.y, a1r = cr.z, a1i = cr.w;
    long base = ((long)b * T_LEN + (long)c * CL) * 256 + hp;
#pragma unroll 4
    for (int i = 0; i < CL; ++i) {
        ushort4 v = xs4[base + (long)i * 256];
        float u0r = bf2f(v.x), u0i = bf2f(v.y), u1r = bf2f(v.z), u1i = bf2f(v.w);
        float n0r = fmaf(lre0, a0r, fmaf(-lim0, a0i, u0r));
        float n0i = fmaf(lre0, a0i, fmaf(lim0, a0r, u0i));
        float n1r = fmaf(lre1, a1r, fmaf(-lim1, a1i, u1r));
        float n1i = fmaf(lre1, a1i, fmaf(lim1, a1r, u1i));
        a0r = n0r; a0i = n0i; a1r = n1r; a1i = n1i;
        ushort4 o;
        o.x = f2bf(a0r); o.y = f2bf(a0i); o.z = f2bf(a1r); o.w = f2bf(a1i);
        xs4[base + (long)i * 256] = o;
    }
}

extern "C" void kernel_launch(void* const* d_in, const int* in_sizes, int n_in,
                              void* d_out, int out_size, void* d_ws, size_t ws_size,
                              hipStream_t stream) {
    const float* x         = (const float*)d_in[0];
    const float* Bre       = (const float*)d_in[1];
    const float* Bim       = (const float*)d_in[2];
    const float* Cre       = (const float*)d_in[3];
    const float* Cim       = (const float*)d_in[4];
    const float* Dv        = (const float*)d_in[5];
    const float* nu        = (const float*)d_in[6];
    const float* theta     = (const float*)d_in[7];
    const float* gamma_log = (const float*)d_in[8];
    float* y = (float*)d_out;

    // ws layout:
    //   [0, 64MB)      xs (bf16 interleaved re,im)
    //   [64MB, 66MB)   region A: BT1 (0.5MB) -> CT (0.5MB, after K1)
    //   [66MB, 68MB)   region B: carry (1MB) | sums (1MB)   <- sums moved out of
    //                  region A: K1 now WRITES sums while READING BT1
    //   [68MB, 84MB)   xb (bf16 x) IF ws_size permits, else xb lives in d_out
    const size_t XS_BYTES  = (size_t)ROWS * H_DIM * 4;
    const size_t REG_BYTES = 2u * 1024 * 1024;
    const size_t XB_BYTES  = (size_t)ROWS * N_DIM * 2;
    unsigned short* xs_us = (unsigned short*)d_ws;
    ushort4* xs4   = (ushort4*)d_ws;
    char* regionA  = (char*)d_ws + XS_BYTES;
    char* regionB  = regionA + REG_BYTES;
    unsigned short* BT1 = (unsigned short*)regionA;
    unsigned short* CT  = (unsigned short*)regionA;
    float4*  carry = (float4*)regionB;
    float4*  sums  = (float4*)(regionB + 1024 * 1024);

    const bool xb_in_ws = ws_size >= XS_BYTES + 2 * REG_BYTES + XB_BYTES;
    unsigned short* xb = xb_in_ws ? (unsigned short*)(regionB + REG_BYTES)
                                  : (unsigned short*)d_out;

    conv_x<<<ROWS * N_DIM / 4 / 256, 256, 0, stream>>>((const float4*)x, (ushort4*)xb);
    conv_Bt<<<(N_DIM * H_DIM) / 256, 256, 0, stream>>>(Bre, Bim, BT1);

    // K1: xs = gamma * (u @ Bint) + fused chunk sums   M=32768 N=1024 K=256
    gemm_mfma<0><<<(ROWS / BM) * (1024 / BN), 256, 0, stream>>>(
        xb, BT1, ROWS, 1024, 256, gamma_log, nullptr, nullptr, nu, theta, sums, xs_us);

    // scan: k2s is fused into K1's epilogue; carries then fused local scan
    k2b_carry<<<(B_SZ * 256) / 256, 256, 0, stream>>>(sums, carry, nu, theta);
    k2ac_scan<<<(B_SZ * NC * 256) / 256, 256, 0, stream>>>(xs4, carry, nu, theta);

    // CT overwrites BT1 region (dead after K1)
    conv_Ct<<<(H_DIM * N_DIM) / 256, 256, 0, stream>>>(Cre, Cim, CT);

    // K3: y = Re(xs @ C) + D*u      M=32768 N=256 K=1024
    gemm_mfma<1><<<(ROWS / BM) * (256 / BN), 256, 0, stream>>>(
        xs_us, CT, ROWS, 256, 1024, Dv, x, xb_in_ws ? xb : nullptr, nullptr, nullptr, nullptr, y);
}